// Round 2
// baseline (5665.093 us; speedup 1.0000x reference)
//
#include <hip/hip_runtime.h>
#include <math.h>

#define BATCH 128
#define PATT 36
#define P_TOT 37
#define FDIM 2048
#define EDIM 1024
#define DDIM 1024
#define ADIM 1024
#define VOCAB 10000
#define LCAP 20
#define TSTEPS 19

typedef __attribute__((ext_vector_type(8))) short bf16x8v;
typedef __attribute__((ext_vector_type(4))) float f32x4v;

__device__ __forceinline__ ushort f2bf(float f) {
  unsigned u = __float_as_uint(f);
  unsigned r = (u + 0x7fffu + ((u >> 16) & 1u)) >> 16;   // RNE
  return (ushort)r;
}
__device__ __forceinline__ float bf2f(ushort u) {
  return __uint_as_float(((unsigned)u) << 16);
}

// async global -> LDS, 16B per lane. LDS dest must be wave-uniform base + lane*16.
__device__ __forceinline__ void gld16(const ushort* g, ushort* l) {
  __builtin_amdgcn_global_load_lds(
      (const __attribute__((address_space(1))) unsigned int*)(g),
      (__attribute__((address_space(3))) unsigned int*)(l), 16, 0, 0);
}

// wait until `cnt` stages (6 loads each) remain in flight
__device__ __forceinline__ void wait_stages(int cnt) {
  if (cnt >= 2)      asm volatile("s_waitcnt vmcnt(12)" ::: "memory");
  else if (cnt == 1) asm volatile("s_waitcnt vmcnt(6)"  ::: "memory");
  else               asm volatile("s_waitcnt vmcnt(0)"  ::: "memory");
}

// ---------------------------------------------------------------------------
// setup: parallel stable rank sort by descending length + permuted LSTM biases
// ---------------------------------------------------------------------------
__global__ void setup_kernel(const int* __restrict__ cap_len,
                             const int* __restrict__ enc_caps,
                             int* __restrict__ sort_ind, int* __restrict__ dec_len,
                             float* __restrict__ out_enc, float* __restrict__ out_dec,
                             float* __restrict__ out_si,
                             const float* __restrict__ bll, const float* __restrict__ bal,
                             float* __restrict__ bll_p, float* __restrict__ bal_p) {
  __shared__ int s_len[BATCH];
  __shared__ int s_ind[BATCH];
  int tid = threadIdx.x;
  if (tid < BATCH) s_len[tid] = cap_len[tid];
  __syncthreads();
  if (tid < BATCH) {
    int key = s_len[tid];
    int pos = 0;
#pragma unroll 8
    for (int j = 0; j < BATCH; ++j) {
      int lj = s_len[j];
      pos += (lj > key) || (lj == key && j < tid);   // stable descending rank
    }
    s_ind[pos] = tid;
  }
  __syncthreads();
  for (int i = tid; i < BATCH; i += blockDim.x) {
    int si = s_ind[i];
    sort_ind[i] = si;
    int dl = s_len[si] - 1;
    dec_len[i] = dl;
    out_dec[i] = (float)dl;
    out_si[i] = (float)si;
  }
  for (int i = tid; i < BATCH * LCAP; i += blockDim.x) {
    int b = i / LCAP, l = i - b * LCAP;
    out_enc[i] = (float)enc_caps[s_ind[b] * LCAP + l];
  }
  // permuted biases: p = 4j+g  <-  orig g*1024+j
  for (int p = tid; p < 4096; p += blockDim.x) {
    int src = (p & 3) * 1024 + (p >> 2);
    bll_p[p] = bll[src];
    bal_p[p] = bal[src];
  }
}

// ---------------------------------------------------------------------------
// fp32 -> bf16 weight conversion; rl!=0 => gate-interleave row permutation
// (row r of rowlen 2^rl: r = g*1024+j  ->  4j+g)
// ---------------------------------------------------------------------------
struct Seg { const float* src; ushort* dst; unsigned n; unsigned rl; };
struct SegTab { Seg s[12]; };

__global__ __launch_bounds__(256) void convert_kernel(SegTab tab) {
  Seg sg = tab.s[blockIdx.y];
  unsigned i0 = (blockIdx.x * 256u + threadIdx.x) * 8u;
  if (i0 >= sg.n) return;
  float4 f0 = *(const float4*)(sg.src + i0);
  float4 f1 = *(const float4*)(sg.src + i0 + 4);
  ushort r[8];
  r[0] = f2bf(f0.x); r[1] = f2bf(f0.y); r[2] = f2bf(f0.z); r[3] = f2bf(f0.w);
  r[4] = f2bf(f1.x); r[5] = f2bf(f1.y); r[6] = f2bf(f1.z); r[7] = f2bf(f1.w);
  unsigned dsti = i0;
  if (sg.rl) {
    unsigned rw = i0 >> sg.rl;
    unsigned col = i0 & ((1u << sg.rl) - 1u);
    dsti = ((4u * (rw & 1023u) + (rw >> 10)) << sg.rl) + col;
  }
  *(uint4*)(sg.dst + dsti) = *(uint4*)r;
}

// img_cat[b*37+p][:] = bf16(concat(img_att, img_fc)[b][p][:])
__global__ __launch_bounds__(256) void img_cat_kernel(const float* __restrict__ img_att,
                                                      const float* __restrict__ img_fc,
                                                      ushort* __restrict__ img_cat) {
  int b = blockIdx.x, p = blockIdx.y;
  const float* src = (p < PATT) ? img_att + ((size_t)b * PATT + p) * FDIM
                                : img_fc + (size_t)b * FDIM;
  ushort* dst = img_cat + ((size_t)b * P_TOT + p) * FDIM;
  int i0 = threadIdx.x * 8;
  float4 f0 = *(const float4*)(src + i0);
  float4 f1 = *(const float4*)(src + i0 + 4);
  ushort r[8];
  r[0] = f2bf(f0.x); r[1] = f2bf(f0.y); r[2] = f2bf(f0.z); r[3] = f2bf(f0.w);
  r[4] = f2bf(f1.x); r[5] = f2bf(f1.y); r[6] = f2bf(f1.z); r[7] = f2bf(f1.w);
  *(uint4*)(dst + i0) = *(uint4*)r;
}

// ---------------------------------------------------------------------------
// bf16 MFMA GEMM, tile 128M x 64N, K-chunk 64, depth-3 pipeline (4 LDS bufs,
// counted vmcnt), XOR-swizzled LDS (both-sides). Optional modes:
//  - gather: A rows assembled from up to 4 source segments (per-row bases in LDS)
//  - lstm:   epilogue applies LSTM cell (gate-interleaved N layout) -> h,c,hbf
//  - ysplit: blocks y>=ysplit use alternate X/W/bias/Cb (merged small GEMMs)
// ---------------------------------------------------------------------------
struct GatherX {
  const ushort* p[4];
  int kend[4];
  int rstride[4];
  int mode[4];     // 0: row=b   1: row=enc_caps[sort_ind[b]*LCAP+t]   2: img_fc row of sort_ind[b]
  int nseg;        // 0 = disabled
};

__global__ __launch_bounds__(256) void gemm_mfma_kernel(
    const ushort* __restrict__ Xp, int ldx,
    const ushort* __restrict__ Wap, int Ka,
    const ushort* __restrict__ Wb, int Kb,
    const float* __restrict__ bias1p, const float* __restrict__ bias2,
    float* __restrict__ C, ushort* __restrict__ Cbp, long ldc,
    int N, int relu, const int* __restrict__ dec_len, int t,
    GatherX gx, const int* __restrict__ sort_ind_g, const int* __restrict__ enc_caps_g,
    float* __restrict__ lstm_h, float* __restrict__ lstm_c, ushort* __restrict__ lstm_hbf,
    const ushort* __restrict__ Xalt, const ushort* __restrict__ Waalt,
    const float* __restrict__ biasalt, ushort* __restrict__ Cbalt, int ysplit)
{
  __shared__ __align__(16) ushort s_A[4][128][64];   // 64 KB
  __shared__ __align__(16) ushort s_B[4][64][64];    // 32 KB
  __shared__ const ushort* s_rowbase[4][128];        // 4 KB

  const ushort* X = Xp;
  const ushort* Wa = Wap;
  const float* bias1 = bias1p;
  ushort* Cb = Cbp;
  int by = blockIdx.y;
  if (ysplit && by >= ysplit) {
    X = Xalt; Wa = Waalt; bias1 = biasalt; Cb = Cbalt; by -= ysplit;
  }

  const int tid = threadIdx.x;
  const int lane = tid & 63;
  const int wv = tid >> 6;
  const int wm = wv >> 1;          // 0..1 : m-half (64 rows)
  const int wn = wv & 1;           // 0..1 : n-half (32 cols)
  const int q = lane >> 4;         // quad 0..3
  const int c16 = lane & 15;

  const int bm = blockIdx.x * 128;
  const int bn = by * 64;
  const int K = Ka + Kb;
  const int nt = K >> 6;
  const bool gather = gx.nseg > 0;

  if (gather) {
    for (int r = tid; r < 128; r += 256) {
      int si = sort_ind_g[r];
      for (int sgi = 0; sgi < gx.nseg; ++sgi) {
        const ushort* bp;
        int m = gx.mode[sgi];
        if (m == 0)      bp = gx.p[sgi] + (size_t)r * gx.rstride[sgi];
        else if (m == 1) bp = gx.p[sgi] + (size_t)enc_caps_g[si * LCAP + t] * gx.rstride[sgi];
        else             bp = gx.p[sgi] + ((size_t)si * P_TOT + PATT) * gx.rstride[sgi];
        s_rowbase[sgi][r] = bp;
      }
    }
    __syncthreads();
  }

  f32x4v acc[4][2];
#pragma unroll
  for (int i = 0; i < 4; ++i)
#pragma unroll
    for (int j = 0; j < 2; ++j) acc[i][j] = (f32x4v){0.f, 0.f, 0.f, 0.f};

  auto stage = [&](int s, int tch) {
    const int k0 = tch << 6;
    if (gather) {
      int sg = 0;
#pragma unroll
      for (int z = 0; z < 3; ++z)
        if (sg + 1 < gx.nseg && k0 >= gx.kend[sg]) ++sg;
      const int kst = sg ? gx.kend[sg - 1] : 0;
#pragma unroll
      for (int i = 0; i < 4; ++i) {
        int gid = i * 256 + tid;
        int r = gid >> 3, gp = gid & 7, gl = gp ^ (r & 7);
        gld16(s_rowbase[sg][r] + (k0 - kst) + gl * 8, &s_A[s][r][gp * 8]);
      }
    } else {
#pragma unroll
      for (int i = 0; i < 4; ++i) {
        int gid = i * 256 + tid;
        int r = gid >> 3, gp = gid & 7, gl = gp ^ (r & 7);
        gld16(X + (size_t)(bm + r) * ldx + k0 + gl * 8, &s_A[s][r][gp * 8]);
      }
    }
#pragma unroll
    for (int i = 0; i < 2; ++i) {
      int gid = i * 256 + tid;
      int r = gid >> 3, gp = gid & 7, gl = gp ^ (r & 7);
      int gn = bn + r;
      if (gn >= N) gn = N - 1;          // clamp; garbage cols skipped in epilogue
      int kk = k0 + gl * 8;
      const ushort* src = (kk < Ka) ? Wa + (size_t)gn * Ka + kk
                                    : Wb + (size_t)gn * Kb + (kk - Ka);
      gld16(src, &s_B[s][r][gp * 8]);
    }
  };

  auto compute = [&](int s) {
#pragma unroll
    for (int ks = 0; ks < 2; ++ks) {
      const int gpa = ((ks << 2) + q) ^ (c16 & 7);   // swizzled read granule
      bf16x8v a[4], b2[2];
#pragma unroll
      for (int mf = 0; mf < 4; ++mf)
        a[mf] = *(const bf16x8v*)&s_A[s][wm * 64 + mf * 16 + c16][gpa * 8];
#pragma unroll
      for (int nf = 0; nf < 2; ++nf)
        b2[nf] = *(const bf16x8v*)&s_B[s][wn * 32 + nf * 16 + c16][gpa * 8];
#pragma unroll
      for (int mf = 0; mf < 4; ++mf)
#pragma unroll
        for (int nf = 0; nf < 2; ++nf)
          acc[mf][nf] = __builtin_amdgcn_mfma_f32_16x16x32_bf16(a[mf], b2[nf], acc[mf][nf], 0, 0, 0);
    }
  };

  // ---- prologue: fill pipeline up to 3 deep ----
  const int pre = nt < 3 ? nt : 3;
  for (int s2 = 0; s2 < pre; ++s2) stage(s2, s2);
  wait_stages(pre - 1);
  __builtin_amdgcn_s_barrier();
  asm volatile("" ::: "memory");

  for (int k = 0; k < nt; ++k) {
    if (k + 3 < nt) stage((k + 3) & 3, k + 3);
    compute(k & 3);
    int li = (k + 3 < nt) ? (k + 3) : (nt - 1);
    int cnt = li - (k + 1);
    if (cnt < 0) cnt = 0;
    wait_stages(cnt);
    __builtin_amdgcn_s_barrier();
    asm volatile("" ::: "memory");
  }

  if (lstm_h) {
    // ---- fused LSTM epilogue (gate-interleaved cols: p = 4j+g) ----
    float* ft = (float*)&s_A[0][0][0];               // 128 x 64 fp32 tile
#pragma unroll
    for (int nf = 0; nf < 2; ++nf) {
      int lc = wn * 32 + nf * 16 + c16;
      float bsum = bias1[bn + lc];
#pragma unroll
      for (int mf = 0; mf < 4; ++mf)
#pragma unroll
        for (int rr = 0; rr < 4; ++rr) {
          int lr = wm * 64 + mf * 16 + q * 4 + rr;
          ft[lr * 64 + lc] = acc[mf][nf][rr] + bsum;
        }
    }
    __syncthreads();
    const int j0 = bn >> 2;
#pragma unroll
    for (int uu = 0; uu < 8; ++uu) {
      int u = uu * 256 + tid;
      int b = u >> 4, jj = u & 15;
      float gi_ = ft[b * 64 + jj * 4 + 0];
      float gf_ = ft[b * 64 + jj * 4 + 1];
      float gg_ = ft[b * 64 + jj * 4 + 2];
      float go_ = ft[b * 64 + jj * 4 + 3];
      float siv = 1.f / (1.f + expf(-gi_));
      float sfv = 1.f / (1.f + expf(-gf_));
      float sov = 1.f / (1.f + expf(-go_));
      int idx = b * 1024 + j0 + jj;
      float co = lstm_c[idx];
      float cn = sfv * co + siv * tanhf(gg_);
      float hn = sov * tanhf(cn);
      bool act = t < dec_len[b];
      float hw = act ? hn : lstm_h[idx];
      float cw = act ? cn : co;
      lstm_h[idx] = hw;
      lstm_c[idx] = cw;
      lstm_hbf[idx] = f2bf(hw);
    }
    return;
  }

  // ---- normal epilogue: C/D layout col=lane&15, row=quad*4+reg ----
#pragma unroll
  for (int nf = 0; nf < 2; ++nf) {
    int gcol = bn + wn * 32 + nf * 16 + c16;
    if (gcol >= N) continue;
    float bsum = bias1[gcol] + (bias2 ? bias2[gcol] : 0.f);
#pragma unroll
    for (int mf = 0; mf < 4; ++mf) {
#pragma unroll
      for (int rr = 0; rr < 4; ++rr) {
        int grow = bm + wm * 64 + mf * 16 + q * 4 + rr;
        float v = acc[mf][nf][rr] + bsum;
        if (relu) v = fmaxf(v, 0.f);
        if (dec_len && !(t < dec_len[grow])) v = 0.f;
        if (C)  C[(size_t)grow * ldc + gcol] = v;
        if (Cb) Cb[(size_t)grow * ldc + gcol] = f2bf(v);
      }
    }
  }
}

// ---------------------------------------------------------------------------
// attention: scores -> softmax -> alphas out (masked) -> awe (row stride 2048)
// ---------------------------------------------------------------------------
__global__ __launch_bounds__(256) void attention_kernel(
    const ushort* __restrict__ att1, const float* __restrict__ d12,
    const float* __restrict__ Wfull, const float* __restrict__ bfull,
    const ushort* __restrict__ img_cat,
    const int* __restrict__ sort_ind, const int* __restrict__ dec_len,
    ushort* __restrict__ x2awe, float* __restrict__ out_alphas, int t) {
  int b = blockIdx.x;
  int si = sort_ind[b];
  __shared__ float dsh[ADIM];
  __shared__ float sc[P_TOT];
  __shared__ float al[P_TOT + 3];
  int tid = threadIdx.x;
  for (int k = tid; k < ADIM; k += 256) dsh[k] = d12[b * ADIM + k];
  __syncthreads();
  int wave = tid >> 6, lane = tid & 63;
  for (int p = wave; p < P_TOT; p += 4) {
    const ushort* arow = att1 + ((size_t)si * P_TOT + p) * ADIM;
    float s = 0.f;
    for (int k = lane * 4; k < ADIM; k += 256) {
      ushort4 av = *(const ushort4*)&arow[k];
      float e0 = fmaxf(bf2f(av.x) + dsh[k + 0], 0.f);
      float e1 = fmaxf(bf2f(av.y) + dsh[k + 1], 0.f);
      float e2 = fmaxf(bf2f(av.z) + dsh[k + 2], 0.f);
      float e3 = fmaxf(bf2f(av.w) + dsh[k + 3], 0.f);
      s += e0 * Wfull[k] + e1 * Wfull[k + 1] + e2 * Wfull[k + 2] + e3 * Wfull[k + 3];
    }
    for (int off = 32; off; off >>= 1) s += __shfl_down(s, off, 64);
    if (lane == 0) sc[p] = s + bfull[0];
  }
  __syncthreads();
  if (tid == 0) {
    float mx = sc[0];
    for (int p = 1; p < P_TOT; ++p) mx = fmaxf(mx, sc[p]);
    float sum = 0.f;
    for (int p = 0; p < P_TOT; ++p) { float e = expf(sc[p] - mx); al[p] = e; sum += e; }
    float inv = 1.f / sum;
    for (int p = 0; p < P_TOT; ++p) al[p] *= inv;
  }
  __syncthreads();
  bool act = t < dec_len[b];
  if (tid < P_TOT)
    out_alphas[((size_t)b * TSTEPS + t) * P_TOT + tid] = act ? al[tid] : 0.f;
  for (int f0 = tid * 4; f0 < FDIM; f0 += 1024) {
    float a0 = 0.f, a1 = 0.f, a2 = 0.f, a3 = 0.f;
#pragma unroll 4
    for (int p = 0; p < P_TOT; ++p) {
      ushort4 iv = *(const ushort4*)&img_cat[((size_t)si * P_TOT + p) * FDIM + f0];
      float w = al[p];
      a0 += w * bf2f(iv.x); a1 += w * bf2f(iv.y);
      a2 += w * bf2f(iv.z); a3 += w * bf2f(iv.w);
    }
    ushort* dst = x2awe + (size_t)b * 2048 + f0;
    dst[0] = f2bf(a0); dst[1] = f2bf(a1); dst[2] = f2bf(a2); dst[3] = f2bf(a3);
  }
}

// ---------------------------------------------------------------------------
extern "C" void kernel_launch(void* const* d_in, const int* in_sizes, int n_in,
                              void* d_out, int out_size, void* d_ws, size_t ws_size,
                              hipStream_t stream) {
  const float* img_att = (const float*)d_in[0];
  const float* img_fc  = (const float*)d_in[1];
  const int*   enc_caps= (const int*)d_in[2];
  const int*   cap_len = (const int*)d_in[3];
  const float* emb     = (const float*)d_in[4];
  const float* Wfa     = (const float*)d_in[5];
  const float* bfa     = (const float*)d_in[6];
  const float* Wd1     = (const float*)d_in[7];
  const float* bd1     = (const float*)d_in[8];
  const float* Wd2     = (const float*)d_in[9];
  const float* bd2     = (const float*)d_in[10];
  const float* Wfull   = (const float*)d_in[11];
  const float* bfull   = (const float*)d_in[12];
  const float* Wlang   = (const float*)d_in[13];
  const float* blang   = (const float*)d_in[14];
  const float* Watt    = (const float*)d_in[15];
  const float* batt    = (const float*)d_in[16];
  const float* Wout    = (const float*)d_in[17];
  const float* bout    = (const float*)d_in[18];
  const float* Wll_ih  = (const float*)d_in[19];
  const float* Wll_hh  = (const float*)d_in[20];
  const float* bll     = (const float*)d_in[21];
  const float* Wal_ih  = (const float*)d_in[22];
  const float* Wal_hh  = (const float*)d_in[23];
  const float* bal     = (const float*)d_in[24];
  const float* Wfc     = (const float*)d_in[25];
  const float* bfc     = (const float*)d_in[26];

  // ---- workspace layout ----
  int* sort_ind = (int*)d_ws;
  int* dec_len  = sort_ind + BATCH;
  const size_t BD = (size_t)BATCH * DDIM;
  float* fbase = (float*)d_ws + 256;
  float* h1    = fbase;
  float* c1    = h1 + BD;
  float* h2    = c1 + BD;
  float* c2    = h2 + BD;
  float* d12   = c2 + BD;
  float* bll_p = d12 + BD;
  float* bal_p = bll_p + 4096;
  ushort* ubase = (ushort*)(bal_p + 4096);
  ushort* h1bfA = ubase;
  ushort* h1bfB = h1bfA + BD;
  ushort* h2bfA = h1bfB + BD;
  ushort* h2bfB = h2bfA + BD;
  ushort* x2awe = h2bfB + BD;                       // 128*2048
  ushort* hid_bf = x2awe + (size_t)BATCH * 2048;    // BD
  ushort* att1_bf = hid_bf + BD;
  ushort* img_cat = att1_bf + (size_t)BATCH * P_TOT * ADIM;
  ushort* emb_bf  = img_cat + (size_t)BATCH * P_TOT * FDIM;
  ushort* wb     = emb_bf + (size_t)VOCAB * EDIM;
  ushort* Wfa_b  = wb;                 wb += (size_t)ADIM * FDIM;
  ushort* Wd1_b  = wb;                 wb += (size_t)ADIM * DDIM;
  ushort* Wd2_b  = wb;                 wb += (size_t)ADIM * DDIM;
  ushort* Wlang_b= wb;                 wb += (size_t)512 * DDIM;
  ushort* Watt_b = wb;                 wb += (size_t)512 * DDIM;
  ushort* Wout_b = wb;                 wb += (size_t)VOCAB * 1024;
  ushort* Wll_ih_b = wb;               wb += (size_t)4096 * 4096;
  ushort* Wll_hh_b = wb;               wb += (size_t)4096 * 1024;
  ushort* Wal_ih_b = wb;               wb += (size_t)4096 * 2048;
  ushort* Wal_hh_b = wb;               wb += (size_t)4096 * 1024;
  ushort* Wfc_b  = wb;                 wb += (size_t)VOCAB * 1024;

  // ---- output layout ----
  float* out      = (float*)d_out;
  float* out_pred = out;
  float* out_pred1= out_pred  + (size_t)BATCH * TSTEPS * VOCAB;
  float* out_enc  = out_pred1 + (size_t)BATCH * TSTEPS * VOCAB;
  float* out_dec  = out_enc + (size_t)BATCH * LCAP;
  float* out_alph = out_dec + BATCH;
  float* out_si   = out_alph + (size_t)BATCH * TSTEPS * P_TOT;

  setup_kernel<<<1, 256, 0, stream>>>(cap_len, enc_caps, sort_ind, dec_len,
                                      out_enc, out_dec, out_si, bll, bal, bll_p, bal_p);
  hipMemsetAsync(h1, 0, 4 * BD * sizeof(float), stream);     // h1,c1,h2,c2
  hipMemsetAsync(h1bfA, 0, 4 * BD * sizeof(ushort), stream); // all 4 bf16 state bufs

  SegTab tab;
  tab.s[0]  = {Wfa,    Wfa_b,    (unsigned)(ADIM * FDIM),  0};
  tab.s[1]  = {Wd1,    Wd1_b,    (unsigned)(ADIM * DDIM),  0};
  tab.s[2]  = {Wd2,    Wd2_b,    (unsigned)(ADIM * DDIM),  0};
  tab.s[3]  = {Wlang,  Wlang_b,  (unsigned)(512 * DDIM),   0};
  tab.s[4]  = {Watt,   Watt_b,   (unsigned)(512 * DDIM),   0};
  tab.s[5]  = {Wout,   Wout_b,   (unsigned)(VOCAB * 1024), 0};
  tab.s[6]  = {Wfc,    Wfc_b,    (unsigned)(VOCAB * 1024), 0};
  tab.s[7]  = {Wll_ih, Wll_ih_b, (unsigned)(4096 * 4096),  12};
  tab.s[8]  = {Wll_hh, Wll_hh_b, (unsigned)(4096 * 1024),  10};
  tab.s[9]  = {Wal_ih, Wal_ih_b, (unsigned)(4096 * 2048),  11};
  tab.s[10] = {Wal_hh, Wal_hh_b, (unsigned)(4096 * 1024),  10};
  tab.s[11] = {emb,    emb_bf,   (unsigned)(VOCAB * EDIM), 0};
  convert_kernel<<<dim3(8192, 12), 256, 0, stream>>>(tab);

  img_cat_kernel<<<dim3(BATCH, P_TOT), 256, 0, stream>>>(img_att, img_fc, img_cat);

  GatherX g0 = {};   // disabled

  // att1 = img_cat @ Wfa^T + bfa  -> bf16  (M=4736, N=1024, K=2048)
  gemm_mfma_kernel<<<dim3(37, 16), 256, 0, stream>>>(
      img_cat, FDIM, Wfa_b, FDIM, nullptr, 0, bfa, nullptr,
      nullptr, att1_bf, ADIM, ADIM, 0, nullptr, 0,
      g0, sort_ind, enc_caps, nullptr, nullptr, nullptr,
      nullptr, nullptr, nullptr, nullptr, 0);

  const long ldo = (long)TSTEPS * VOCAB;
  ushort *h1r = h1bfA, *h1w = h1bfB, *h2r = h2bfA, *h2w = h2bfB;

  for (int t = 0; t < TSTEPS; ++t) {
    // gates1+lstm1: x1=[emb|h2old|img_fc|h1old] @ perm([Wll_ih|Wll_hh])^T (N=4096,K=5120)
    GatherX g1;
    g1.p[0] = emb_bf;  g1.kend[0] = 1024; g1.rstride[0] = EDIM; g1.mode[0] = 1;
    g1.p[1] = h2r;     g1.kend[1] = 2048; g1.rstride[1] = DDIM; g1.mode[1] = 0;
    g1.p[2] = img_cat; g1.kend[2] = 4096; g1.rstride[2] = FDIM; g1.mode[2] = 2;
    g1.p[3] = h1r;     g1.kend[3] = 5120; g1.rstride[3] = DDIM; g1.mode[3] = 0;
    g1.nseg = 4;
    gemm_mfma_kernel<<<dim3(1, 64), 256, 0, stream>>>(
        nullptr, 0, Wll_ih_b, 4096, Wll_hh_b, 1024, bll_p, nullptr,
        nullptr, nullptr, 0, 4096, 0, dec_len, t,
        g1, sort_ind, enc_caps, h1, c1, h1w,
        nullptr, nullptr, nullptr, nullptr, 0);

    // preds1 = h1new @ Wfc^T + bfc  (masked, N=10000, K=1024)
    gemm_mfma_kernel<<<dim3(1, 157), 256, 0, stream>>>(
        h1w, 1024, Wfc_b, 1024, nullptr, 0, bfc, nullptr,
        out_pred1 + (size_t)t * VOCAB, nullptr, ldo, VOCAB, 0, dec_len, t,
        g0, sort_ind, enc_caps, nullptr, nullptr, nullptr,
        nullptr, nullptr, nullptr, nullptr, 0);

    // d12 = [h1new|h2old] @ [Wd1|Wd2]^T + bd1 + bd2  (N=1024, K=2048)
    GatherX g2;
    g2.p[0] = h1w; g2.kend[0] = 1024; g2.rstride[0] = DDIM; g2.mode[0] = 0;
    g2.p[1] = h2r; g2.kend[1] = 2048; g2.rstride[1] = DDIM; g2.mode[1] = 0;
    g2.nseg = 2;
    gemm_mfma_kernel<<<dim3(1, 16), 256, 0, stream>>>(
        nullptr, 0, Wd1_b, 1024, Wd2_b, 1024, bd1, bd2,
        d12, nullptr, 1024, 1024, 0, nullptr, 0,
        g2, sort_ind, enc_caps, nullptr, nullptr, nullptr,
        nullptr, nullptr, nullptr, nullptr, 0);

    attention_kernel<<<BATCH, 256, 0, stream>>>(
        att1_bf, d12, Wfull, bfull, img_cat, sort_ind, dec_len,
        x2awe, out_alph, t);

    // gates2+lstm2: [awe|h2old] @ perm([Wal_ih|Wal_hh])^T (N=4096, K=3072)
    GatherX g3;
    g3.p[0] = x2awe; g3.kend[0] = 2048; g3.rstride[0] = 2048; g3.mode[0] = 0;
    g3.p[1] = h2r;   g3.kend[1] = 3072; g3.rstride[1] = DDIM; g3.mode[1] = 0;
    g3.nseg = 2;
    gemm_mfma_kernel<<<dim3(1, 64), 256, 0, stream>>>(
        nullptr, 0, Wal_ih_b, 2048, Wal_hh_b, 1024, bal_p, nullptr,
        nullptr, nullptr, 0, 4096, 0, dec_len, t,
        g3, sort_ind, enc_caps, h2, c2, h2w,
        nullptr, nullptr, nullptr, nullptr, 0);

    // hid = relu([h1new @ Wlang^T + blang | h2new @ Watt^T + batt]) merged (2x N=512)
    gemm_mfma_kernel<<<dim3(1, 16), 256, 0, stream>>>(
        h1w, 1024, Wlang_b, 1024, nullptr, 0, blang, nullptr,
        nullptr, hid_bf, 1024, 512, 1, nullptr, 0,
        g0, sort_ind, enc_caps, nullptr, nullptr, nullptr,
        h2w, Watt_b, batt, hid_bf + 512, 8);

    // out = hid @ Wout^T + bout  (masked, N=10000, K=1024)
    gemm_mfma_kernel<<<dim3(1, 157), 256, 0, stream>>>(
        hid_bf, 1024, Wout_b, 1024, nullptr, 0, bout, nullptr,
        out_pred + (size_t)t * VOCAB, nullptr, ldo, VOCAB, 0, dec_len, t,
        g0, sort_ind, enc_caps, nullptr, nullptr, nullptr,
        nullptr, nullptr, nullptr, nullptr, 0);

    // ping-pong bf16 state
    ushort* tmp;
    tmp = h1r; h1r = h1w; h1w = tmp;
    tmp = h2r; h2r = h2w; h2w = tmp;
  }
}